// Round 2
// baseline (220.559 us; speedup 1.0000x reference)
//
#include <hip/hip_runtime.h>
#include <hip/hip_bf16.h>
#include <stdint.h>

#define N_SAMPLES 4096
#define M_ROWS 16
#define K_DIM 256
#define H_DIM 256
#define N_CATS 64
#define SPB 4                                        // samples per group (64 rows)
#define MAX_PADDED (N_SAMPLES + N_CATS * (SPB - 1))  // 4288
#define NGROUP (MAX_PADDED / SPB)                    // 1072
#define GPX (NGROUP / 8)                             // 134 groups per XCD
#define GEMM_GRID (NGROUP * 2)                       // 2144 (two h-halves)

typedef _Float16 half8 __attribute__((ext_vector_type(8)));
typedef _Float16 half4 __attribute__((ext_vector_type(4)));
typedef float floatx4 __attribute__((ext_vector_type(4)));

// ---- workspace layout ----
#define WT_BYTES ((size_t)N_CATS * K_DIM * H_DIM * 2)  // 8 MB f16 W^T
#define GCAT_OFF WT_BYTES                              // NGROUP ints (4288 B, 16B-mult)
#define ORD_OFF  (WT_BYTES + 4288)
#define WS_NEED  (ORD_OFF + (size_t)MAX_PADDED * 4)

// ---------------- fused prep: transpose (blocks 0..1023) + bucketing (block 1024) ----
__global__ __launch_bounds__(256)
void prep_combined(const float* __restrict__ W, _Float16* __restrict__ Wt,
                   const int* __restrict__ cat, int* __restrict__ ord,
                   int* __restrict__ gcat) {
  const int tid = threadIdx.x;
  if (blockIdx.x < 1024) {
    __shared__ _Float16 t[64][72];
    const int bid = blockIdx.x;
    const int c  = bid >> 4;
    const int kb = (bid >> 2) & 3;
    const int hb = bid & 3;
    const int r  = tid >> 2;
    const int cg = (tid & 3) * 16;
    const float* src = W + ((size_t)c << 16) + (size_t)(kb * 64 + r) * 256 + hb * 64 + cg;
#pragma unroll
    for (int j = 0; j < 16; j += 4) {
      float4 v = *(const float4*)(src + j);
      t[r][cg + j + 0] = (_Float16)v.x;
      t[r][cg + j + 1] = (_Float16)v.y;
      t[r][cg + j + 2] = (_Float16)v.z;
      t[r][cg + j + 3] = (_Float16)v.w;
    }
    __syncthreads();
    _Float16* dst = Wt + ((size_t)c << 16) + (size_t)(hb * 64 + r) * 256 + kb * 64 + cg;
    half8 o0, o1;
#pragma unroll
    for (int j = 0; j < 8; j++) o0[j] = t[cg + j][r];
#pragma unroll
    for (int j = 0; j < 8; j++) o1[j] = t[cg + 8 + j][r];
    *(half8*)(dst) = o0;
    *(half8*)(dst + 8) = o1;
  } else {
    __shared__ int hist[N_CATS];
    __shared__ int poffs[N_CATS];
    __shared__ int curs[N_CATS];
    if (tid < N_CATS) hist[tid] = 0;
    for (int i = tid; i < MAX_PADDED; i += 256) ord[i] = -1;
    for (int i = tid; i < NGROUP; i += 256) gcat[i] = 0;
    __syncthreads();
    for (int i = tid; i < N_SAMPLES; i += 256) atomicAdd(&hist[cat[i]], 1);
    __syncthreads();
    if (tid == 0) {
      int run = 0;
      for (int c = 0; c < N_CATS; c++) {
        poffs[c] = run;
        run += ((hist[c] + SPB - 1) / SPB) * SPB;
      }
    }
    if (tid < N_CATS) curs[tid] = 0;
    __syncthreads();
    if (tid < N_CATS) {
      const int c = tid;
      const int g0 = poffs[c] >> 2;
      const int ng = (hist[c] + SPB - 1) >> 2;
      for (int g = 0; g < ng; g++) gcat[g0 + g] = c;
    }
    for (int i = tid; i < N_SAMPLES; i += 256) {
      int c = cat[i];
      int p = poffs[c] + atomicAdd(&curs[c], 1);
      ord[p] = i;
    }
  }
}

// ---------------- main GEMM (streaming, no LDS, no barriers) ----------------
// block = 256 thr (4 waves); unit = (group, h-half): 64 rows x 128 cols.
// Wave w owns cols h0 + w*32..+31 for all 4 samples of the group.
// A-fragments load DIRECTLY from global x (fp32) as 2x float4 per (mt,kt):
//   lane reads x[smp][l15][kt*32+quad*8 ..+8]  -> per kt the wave covers
//   16 rows x 128B fully coalesced. fp32->f16 cvt in-register (transient af).
// Explicit even/odd double-buffer for A (static names, no runtime indexing),
// 1-kt lookahead for B. Every wave streams loads continuously: the memory
// pipeline is never drained by a barrier (there are none).
#define ISSUE_A(NXT, ko)                                                         \
  NXT[0][0] = *(const float4*)(a0 + (ko)); NXT[0][1] = *(const float4*)(a0 + (ko) + 4); \
  NXT[1][0] = *(const float4*)(a1 + (ko)); NXT[1][1] = *(const float4*)(a1 + (ko) + 4); \
  NXT[2][0] = *(const float4*)(a2 + (ko)); NXT[2][1] = *(const float4*)(a2 + (ko) + 4); \
  NXT[3][0] = *(const float4*)(a3 + (ko)); NXT[3][1] = *(const float4*)(a3 + (ko) + 4);

#define CVT_MFMA_ONE(CUR, mt, cb)                                                \
  {                                                                              \
    half8 af;                                                                    \
    af[0] = (_Float16)CUR[mt][0].x; af[1] = (_Float16)CUR[mt][0].y;              \
    af[2] = (_Float16)CUR[mt][0].z; af[3] = (_Float16)CUR[mt][0].w;              \
    af[4] = (_Float16)CUR[mt][1].x; af[5] = (_Float16)CUR[mt][1].y;              \
    af[6] = (_Float16)CUR[mt][1].z; af[7] = (_Float16)CUR[mt][1].w;              \
    acc[mt][0] = __builtin_amdgcn_mfma_f32_16x16x32_f16(af, bf[cb][0], acc[mt][0], 0, 0, 0); \
    acc[mt][1] = __builtin_amdgcn_mfma_f32_16x16x32_f16(af, bf[cb][1], acc[mt][1], 0, 0, 0); \
  }

#define KT_STEP(kt, CUR, NXT)                                                    \
  if ((kt) < 7) { ISSUE_A(NXT, ((kt) + 1) * 32); }                               \
  if ((kt) < 7) {                                                                \
    bf[((kt) + 1) & 1][0] = *(const half8*)(wb + ((kt) + 1) * 32);               \
    bf[((kt) + 1) & 1][1] = *(const half8*)(wb + 16 * K_DIM + ((kt) + 1) * 32);  \
  }                                                                              \
  CVT_MFMA_ONE(CUR, 0, (kt) & 1)                                                 \
  CVT_MFMA_ONE(CUR, 1, (kt) & 1)                                                 \
  CVT_MFMA_ONE(CUR, 2, (kt) & 1)                                                 \
  CVT_MFMA_ONE(CUR, 3, (kt) & 1)

__global__ __launch_bounds__(256, 3)
void gemm_kernel(const float* __restrict__ x, const float* __restrict__ bias,
                 const _Float16* __restrict__ Wt, const int* __restrict__ ord,
                 const int* __restrict__ gcat, float* __restrict__ out) {
  const int tid = threadIdx.x;
  const int B = blockIdx.x;
  const int xcd = B & 7;
  const int slot = B >> 3;
  const int h_half = slot & 1;
  const int group = xcd * GPX + (slot >> 1);  // consecutive slots (same cat) -> same XCD
  const int h0 = h_half << 7;

  const int cat = gcat[group];                 // independent of ord (gcat pre-zeroed)
  const int4 sm = *(const int4*)(ord + group * 4);
  if (sm.x < 0) return;                        // fully-padded tail group (uniform)

  const int lane = tid & 63;
  const int wid  = tid >> 6;
  const int l15  = lane & 15;
  const int quad = lane >> 4;

  const _Float16* wb = Wt + ((size_t)cat << 16) +
                       (size_t)(h0 + wid * 32 + l15) * K_DIM + quad * 8;

  // A base pointers (padded rows -> sample 0, result discarded at store)
  const float* a0 = x + ((size_t)sm.x << 12) + l15 * 256 + quad * 8;
  const float* a1 = x + ((size_t)(sm.y < 0 ? 0 : sm.y) << 12) + l15 * 256 + quad * 8;
  const float* a2 = x + ((size_t)(sm.z < 0 ? 0 : sm.z) << 12) + l15 * 256 + quad * 8;
  const float* a3 = x + ((size_t)(sm.w < 0 ? 0 : sm.w) << 12) + l15 * 256 + quad * 8;

  // ---- prologue: B kt0 + A kt0 issued immediately ----
  half8 bf[2][2];
  bf[0][0] = *(const half8*)(wb);
  bf[0][1] = *(const half8*)(wb + 16 * K_DIM);

  float4 arA[4][2], arB[4][2];
  ISSUE_A(arA, 0);

  const float bv0 = bias[cat * H_DIM + h0 + wid * 32 + l15];
  const float bv1 = bias[cat * H_DIM + h0 + wid * 32 + 16 + l15];

  floatx4 acc[4][2];
#pragma unroll
  for (int i = 0; i < 4; i++)
#pragma unroll
    for (int j = 0; j < 2; j++)
#pragma unroll
      for (int e = 0; e < 4; e++) acc[i][j][e] = 0.0f;

  // ---- streaming K loop: fully static even/odd rotation ----
  KT_STEP(0, arA, arB)
  KT_STEP(1, arB, arA)
  KT_STEP(2, arA, arB)
  KT_STEP(3, arB, arA)
  KT_STEP(4, arA, arB)
  KT_STEP(5, arB, arA)
  KT_STEP(6, arA, arB)
  KT_STEP(7, arB, arA)

  // ---- epilogue: C/D layout col=lane&15, row=quad*4+reg ----
  const int srow[4] = {sm.x, sm.y, sm.z, sm.w};
#pragma unroll
  for (int mt = 0; mt < 4; mt++) {
    const int s = srow[mt];
    if (s < 0) continue;
    float* obase = out + ((size_t)s << 12);
#pragma unroll
    for (int nt = 0; nt < 2; nt++) {
      const int col = h0 + wid * 32 + nt * 16 + l15;
      const float bv = nt ? bv1 : bv0;
#pragma unroll
      for (int rr = 0; rr < 4; rr++) {
        const int row = quad * 4 + rr;
        obase[(size_t)row * H_DIM + col] = acc[mt][nt][rr] + bv;
      }
    }
  }
}

// ---------------- fallback (ws too small): naive fp32 ----------------
__global__ __launch_bounds__(256)
void naive_kernel(const float* __restrict__ x, const int* __restrict__ cat,
                  const float* __restrict__ W, const float* __restrict__ bias,
                  float* __restrict__ out) {
  __shared__ float sx[16 * 256];
  const int n = blockIdx.x;
  const int tid = threadIdx.x;
  const int c = cat[n];
  const float* xs = x + (size_t)n * 16 * 256;
  for (int i = tid; i < 16 * 256; i += 256) sx[i] = xs[i];
  __syncthreads();
  const float* Wc = W + ((size_t)c << 16);
  float accv[16];
  float bv = bias[c * 256 + tid];
#pragma unroll
  for (int m = 0; m < 16; m++) accv[m] = bv;
  for (int k = 0; k < 256; k++) {
    float w = Wc[(size_t)k * 256 + tid];
#pragma unroll
    for (int m = 0; m < 16; m++) accv[m] += sx[m * 256 + k] * w;
  }
#pragma unroll
  for (int m = 0; m < 16; m++) out[((size_t)n * 16 + m) * 256 + tid] = accv[m];
}

// ---------------- launcher ----------------
extern "C" void kernel_launch(void* const* d_in, const int* in_sizes, int n_in,
                              void* d_out, int out_size, void* d_ws, size_t ws_size,
                              hipStream_t stream) {
  const float* x    = (const float*)d_in[0];
  const int*   cat  = (const int*)d_in[1];
  const float* W    = (const float*)d_in[2];
  const float* bias = (const float*)d_in[3];
  float* out = (float*)d_out;

  if (ws_size < WS_NEED) {
    naive_kernel<<<N_SAMPLES, 256, 0, stream>>>(x, cat, W, bias, out);
    return;
  }

  char* ws = (char*)d_ws;
  _Float16* Wt = (_Float16*)ws;
  int* gcat = (int*)(ws + GCAT_OFF);
  int* ord  = (int*)(ws + ORD_OFF);

  prep_combined<<<1025, 256, 0, stream>>>(W, Wt, cat, ord, gcat);
  gemm_kernel<<<GEMM_GRID, 256, 0, stream>>>(x, bias, Wt, ord, gcat, out);
}

// Round 3
// 168.176 us; speedup vs baseline: 1.3115x; 1.3115x over previous
//
#include <hip/hip_runtime.h>
#include <hip/hip_bf16.h>
#include <stdint.h>

#define N_SAMPLES 4096
#define M_ROWS 16
#define K_DIM 256
#define H_DIM 256
#define N_CATS 64
#define SPB 4                                        // samples per group (64 rows)
#define MAX_PADDED (N_SAMPLES + N_CATS * (SPB - 1))  // 4288
#define NGROUP (MAX_PADDED / SPB)                    // 1072
#define GPX (NGROUP / 8)                             // 134 groups per XCD

typedef _Float16 half8 __attribute__((ext_vector_type(8)));
typedef _Float16 half4 __attribute__((ext_vector_type(4)));
typedef float floatx4 __attribute__((ext_vector_type(4)));

// async global->LDS DMA, 16B per lane (dest = uniform base + lane*16)
#define GLOAD_LDS(g, l)                                          \
  __builtin_amdgcn_global_load_lds(                              \
      (const __attribute__((address_space(1))) void*)(g),        \
      (__attribute__((address_space(3))) void*)(l), 16, 0, 0)

// ---- workspace layout ----
#define WT_BYTES ((size_t)N_CATS * K_DIM * H_DIM * 2)  // 8 MB f16 W^T
#define GCAT_OFF WT_BYTES                              // NGROUP ints (4288 B, 16B-mult)
#define ORD_OFF  (WT_BYTES + 4288)
#define WS_NEED  (ORD_OFF + (size_t)MAX_PADDED * 4)

// ---------------- fused prep: transpose (blocks 0..1023) + bucketing (block 1024) ----
__global__ __launch_bounds__(256)
void prep_combined(const float* __restrict__ W, _Float16* __restrict__ Wt,
                   const int* __restrict__ cat, int* __restrict__ ord,
                   int* __restrict__ gcat) {
  const int tid = threadIdx.x;
  if (blockIdx.x < 1024) {
    __shared__ _Float16 t[64][72];
    const int bid = blockIdx.x;
    const int c  = bid >> 4;
    const int kb = (bid >> 2) & 3;
    const int hb = bid & 3;
    const int r  = tid >> 2;
    const int cg = (tid & 3) * 16;
    const float* src = W + ((size_t)c << 16) + (size_t)(kb * 64 + r) * 256 + hb * 64 + cg;
#pragma unroll
    for (int j = 0; j < 16; j += 4) {
      float4 v = *(const float4*)(src + j);
      t[r][cg + j + 0] = (_Float16)v.x;
      t[r][cg + j + 1] = (_Float16)v.y;
      t[r][cg + j + 2] = (_Float16)v.z;
      t[r][cg + j + 3] = (_Float16)v.w;
    }
    __syncthreads();
    _Float16* dst = Wt + ((size_t)c << 16) + (size_t)(hb * 64 + r) * 256 + kb * 64 + cg;
    half8 o0, o1;
#pragma unroll
    for (int j = 0; j < 8; j++) o0[j] = t[cg + j][r];
#pragma unroll
    for (int j = 0; j < 8; j++) o1[j] = t[cg + 8 + j][r];
    *(half8*)(dst) = o0;
    *(half8*)(dst + 8) = o1;
  } else {
    __shared__ int hist[N_CATS];
    __shared__ int poffs[N_CATS];
    __shared__ int curs[N_CATS];
    if (tid < N_CATS) hist[tid] = 0;
    for (int i = tid; i < MAX_PADDED; i += 256) ord[i] = -1;
    for (int i = tid; i < NGROUP; i += 256) gcat[i] = 0;
    __syncthreads();
    for (int i = tid; i < N_SAMPLES; i += 256) atomicAdd(&hist[cat[i]], 1);
    __syncthreads();
    if (tid == 0) {
      int run = 0;
      for (int c = 0; c < N_CATS; c++) {
        poffs[c] = run;
        run += ((hist[c] + SPB - 1) / SPB) * SPB;
      }
    }
    if (tid < N_CATS) curs[tid] = 0;
    __syncthreads();
    if (tid < N_CATS) {
      const int c = tid;
      const int g0 = poffs[c] >> 2;
      const int ng = (hist[c] + SPB - 1) >> 2;
      for (int g = 0; g < ng; g++) gcat[g0 + g] = c;
    }
    for (int i = tid; i < N_SAMPLES; i += 256) {
      int c = cat[i];
      int p = poffs[c] + atomicAdd(&curs[c], 1);
      ord[p] = i;
    }
  }
}

// ---------------- main GEMM ----------------
// block = 512 thr (8 waves) = one group: 64 rows (4 samples) x FULL 256 cols.
// Wave w owns cols w*32..+31; A is fetched/staged ONCE per group.
// A: raw fp32 staged via global_load_lds (async DMA, no VGPR round-trip).
//    LDS layout: row-major [64][256] floats with 16B-slot XOR swizzle
//    (slot ^= row&7). DMA dest must be linear -> the GLOBAL source is
//    pre-swizzled per lane: lane reads slot (lane ^ rs), rs = row&7.
//    Wave w stages rows {w, w+8, ..., w+56} so rs == wid (wave-constant).
//    ds_read_b128 at MFMA time: 16 lanes/quad spread over 8 slots = 2-way (free).
//    fp32->f16 cvt (RTE, same numerics as before) happens in-loop, overlapped.
// B: bf[8][2]; kt0-3 issued pre-barrier, kt+4 rolling-prefetched in-loop
//    (4-step lookahead covers L2 latency).
// ONE barrier total; its vmcnt(0) drain is exactly what the DMA needs.
__global__ __launch_bounds__(512, 4)
void gemm_kernel(const float* __restrict__ x, const float* __restrict__ bias,
                 const _Float16* __restrict__ Wt, const int* __restrict__ ord,
                 const int* __restrict__ gcat, float* __restrict__ out) {
  __shared__ __align__(16) float sA[64 * 256];  // 64 KB fp32, swizzled

  const int tid = threadIdx.x;
  const int B = blockIdx.x;
  const int xcd = B & 7;
  const int group = xcd * GPX + (B >> 3);   // contiguous (same-cat) groups per XCD

  const int cat = gcat[group];              // independent of ord (gcat pre-zeroed)
  const int4 sm = *(const int4*)(ord + group * 4);
  if (sm.x < 0) return;                     // fully-padded tail group (block-uniform)

  const int wid  = tid >> 6;                // 0..7
  const int lane = tid & 63;
  const int l15  = lane & 15;
  const int quad = lane >> 4;

  // ---- A staging: wave w DMAs rows {w, w+8, ..., w+56}, source pre-swizzled ----
  const int s0 = sm.x;
  const int s1 = sm.y < 0 ? sm.x : sm.y;
  const int s2 = sm.z < 0 ? sm.x : sm.z;
  const int s3 = sm.w < 0 ? sm.x : sm.w;
  const int lx = (lane ^ wid) << 2;         // this lane's (swizzled) float offset in a row
#pragma unroll
  for (int i = 0; i < 8; i++) {
    // row = i*8+wid; sample idx = row>>4 = i>>1 (compile-time); intra = (i&1)*8+wid
    const int smp = ((i >> 1) == 0) ? s0 : ((i >> 1) == 1) ? s1 : ((i >> 1) == 2) ? s2 : s3;
    const float* gp = x + ((size_t)smp << 12) + (size_t)((i & 1) * 8 + wid) * 256 + lx;
    GLOAD_LDS(gp, sA + (i * 8 + wid) * 256);
  }

  // ---- B fragments kt=0..3 + bias: issued pre-barrier ----
  const _Float16* wb = Wt + ((size_t)cat << 16) + (size_t)(wid * 32 + l15) * K_DIM + quad * 8;
  half8 bf[8][2];
#pragma unroll
  for (int kt = 0; kt < 4; kt++) {
    bf[kt][0] = *(const half8*)(wb + kt * 32);
    bf[kt][1] = *(const half8*)(wb + 16 * K_DIM + kt * 32);
  }
  const float bv0 = bias[cat * H_DIM + wid * 32 + l15];
  const float bv1 = bias[cat * H_DIM + wid * 32 + 16 + l15];

  floatx4 acc[4][2];
#pragma unroll
  for (int i = 0; i < 4; i++)
#pragma unroll
    for (int j = 0; j < 2; j++)
#pragma unroll
      for (int e = 0; e < 4; e++) acc[i][j][e] = 0.0f;

  __syncthreads();  // the ONLY barrier (vmcnt(0) drain completes the DMA + bf kt0-3)

  // ---- MFMA loop: ds_read fp32 (swizzled) -> cvt f16 -> mfma; rolling B prefetch ----
  const int swz = (l15 & 7) << 2;           // float-index XOR (bits 2..4) within a row
#pragma unroll
  for (int kt = 0; kt < 8; kt++) {
    if (kt < 4) {  // prefetch kt+4 (4 groups of lookahead)
      bf[kt + 4][0] = *(const half8*)(wb + (kt + 4) * 32);
      bf[kt + 4][1] = *(const half8*)(wb + 16 * K_DIM + (kt + 4) * 32);
    }
    half8 af[4];
#pragma unroll
    for (int mt = 0; mt < 4; mt++) {
      const float* ap = sA + (size_t)(mt * 16 + l15) * 256;
      float4 f0 = *(const float4*)(ap + ((kt * 32 + quad * 8 + 0) ^ swz));
      float4 f1 = *(const float4*)(ap + ((kt * 32 + quad * 8 + 4) ^ swz));
      af[mt][0] = (_Float16)f0.x; af[mt][1] = (_Float16)f0.y;
      af[mt][2] = (_Float16)f0.z; af[mt][3] = (_Float16)f0.w;
      af[mt][4] = (_Float16)f1.x; af[mt][5] = (_Float16)f1.y;
      af[mt][6] = (_Float16)f1.z; af[mt][7] = (_Float16)f1.w;
    }
#pragma unroll
    for (int mt = 0; mt < 4; mt++) {
      acc[mt][0] = __builtin_amdgcn_mfma_f32_16x16x32_f16(af[mt], bf[kt][0], acc[mt][0], 0, 0, 0);
      acc[mt][1] = __builtin_amdgcn_mfma_f32_16x16x32_f16(af[mt], bf[kt][1], acc[mt][1], 0, 0, 0);
    }
  }

  // ---- epilogue: C/D layout col=lane&15, row=quad*4+reg; nontemporal stores ----
  const int srow[4] = {sm.x, sm.y, sm.z, sm.w};
#pragma unroll
  for (int mt = 0; mt < 4; mt++) {
    const int s = srow[mt];
    if (s < 0) continue;
    float* obase = out + ((size_t)s << 12);
#pragma unroll
    for (int nt = 0; nt < 2; nt++) {
      const int col = wid * 32 + nt * 16 + l15;
      const float bv = nt ? bv1 : bv0;
#pragma unroll
      for (int rr = 0; rr < 4; rr++) {
        const int row = quad * 4 + rr;
        __builtin_nontemporal_store(acc[mt][nt][rr] + bv, obase + (size_t)row * H_DIM + col);
      }
    }
  }
}

// ---------------- fallback (ws too small): naive fp32 ----------------
__global__ __launch_bounds__(256)
void naive_kernel(const float* __restrict__ x, const int* __restrict__ cat,
                  const float* __restrict__ W, const float* __restrict__ bias,
                  float* __restrict__ out) {
  __shared__ float sx[16 * 256];
  const int n = blockIdx.x;
  const int tid = threadIdx.x;
  const int c = cat[n];
  const float* xs = x + (size_t)n * 16 * 256;
  for (int i = tid; i < 16 * 256; i += 256) sx[i] = xs[i];
  __syncthreads();
  const float* Wc = W + ((size_t)c << 16);
  float accv[16];
  float bv = bias[c * 256 + tid];
#pragma unroll
  for (int m = 0; m < 16; m++) accv[m] = bv;
  for (int k = 0; k < 256; k++) {
    float w = Wc[(size_t)k * 256 + tid];
#pragma unroll
    for (int m = 0; m < 16; m++) accv[m] += sx[m * 256 + k] * w;
  }
#pragma unroll
  for (int m = 0; m < 16; m++) out[((size_t)n * 16 + m) * 256 + tid] = accv[m];
}

// ---------------- launcher ----------------
extern "C" void kernel_launch(void* const* d_in, const int* in_sizes, int n_in,
                              void* d_out, int out_size, void* d_ws, size_t ws_size,
                              hipStream_t stream) {
  const float* x    = (const float*)d_in[0];
  const int*   cat  = (const int*)d_in[1];
  const float* W    = (const float*)d_in[2];
  const float* bias = (const float*)d_in[3];
  float* out = (float*)d_out;

  if (ws_size < WS_NEED) {
    naive_kernel<<<N_SAMPLES, 256, 0, stream>>>(x, cat, W, bias, out);
    return;
  }

  char* ws = (char*)d_ws;
  _Float16* Wt = (_Float16*)ws;
  int* gcat = (int*)(ws + GCAT_OFF);
  int* ord  = (int*)(ws + ORD_OFF);

  prep_combined<<<1025, 256, 0, stream>>>(W, Wt, cat, ord, gcat);
  gemm_kernel<<<NGROUP, 512, 0, stream>>>(x, bias, Wt, ord, gcat, out);
}